// Round 10
// baseline (1818.977 us; speedup 1.0000x reference)
//
#include <hip/hip_runtime.h>
#include <stdint.h>

#define B_ 256
#define T_ 512
#define D_ 128
#define H_ 256

typedef __attribute__((ext_vector_type(8))) _Float16 half8;
typedef __attribute__((ext_vector_type(4))) float f32x4;
typedef __attribute__((ext_vector_type(4))) int i32x4;

// ws layout (bytes)
#define WS_PART 0                        // 16*256 floats fc partials
#define WS_H0   65536                    // [2][256][256] u32 (epoch<<16 | f16) layer0 h
#define WS_H1   (65536 + 2*B_*H_*4)      // [3][256][256] u32 layer1 h (TRIPLE buffer)
// end = 65536 + 2*256KB + 3*256KB ≈ 1.34 MB

__device__ __forceinline__ float fast_sig(float x) {
    return 1.0f / (1.0f + __expf(-x));
}
__device__ __forceinline__ float fast_tanh(float x) {
    float xc = fminf(fmaxf(x, -30.0f), 30.0f);
    float e = __expf(-2.0f * xc);
    return (1.0f - e) / (1.0f + e);
}
__device__ __forceinline__ half8 cvt8(const float* p) {
    const f32x4* q = (const f32x4*)p;
    f32x4 a = q[0], b = q[1];
    half8 r;
    r[0] = (_Float16)a[0]; r[1] = (_Float16)a[1];
    r[2] = (_Float16)a[2]; r[3] = (_Float16)a[3];
    r[4] = (_Float16)b[0]; r[5] = (_Float16)b[1];
    r[6] = (_Float16)b[2]; r[7] = (_Float16)b[3];
    return r;
}
__device__ __forceinline__ half8 cvt8v(f32x4 a, f32x4 b) {
    half8 r;
    r[0] = (_Float16)a[0]; r[1] = (_Float16)a[1];
    r[2] = (_Float16)a[2]; r[3] = (_Float16)a[3];
    r[4] = (_Float16)b[0]; r[5] = (_Float16)b[1];
    r[6] = (_Float16)b[2]; r[7] = (_Float16)b[3];
    return r;
}

// ---- MALL-coherent (sc0 sc1) primitives — the ONLY verified cross-CU path ----
__device__ __forceinline__ void poll4_issue(const unsigned* p, i32x4* r) {
    asm volatile(
        "global_load_dwordx4 %0, %4, off sc0 sc1\n\t"
        "global_load_dwordx4 %1, %4, off offset:16 sc0 sc1\n\t"
        "global_load_dwordx4 %2, %4, off offset:128 sc0 sc1\n\t"
        "global_load_dwordx4 %3, %4, off offset:144 sc0 sc1"
        : "=&v"(r[0]), "=&v"(r[1]), "=&v"(r[2]), "=&v"(r[3])
        : "v"(p) : "memory");
}
__device__ __forceinline__ void poll4_wait(const unsigned* p, i32x4* r) {
    asm volatile(
        "global_load_dwordx4 %0, %4, off sc0 sc1\n\t"
        "global_load_dwordx4 %1, %4, off offset:16 sc0 sc1\n\t"
        "global_load_dwordx4 %2, %4, off offset:128 sc0 sc1\n\t"
        "global_load_dwordx4 %3, %4, off offset:144 sc0 sc1\n\t"
        "s_waitcnt vmcnt(0)"
        : "=&v"(r[0]), "=&v"(r[1]), "=&v"(r[2]), "=&v"(r[3])
        : "v"(p) : "memory");
}
__device__ __forceinline__ void wait_tie8(i32x4* a, i32x4* b) {
    asm volatile("s_waitcnt vmcnt(0)"
        : "+v"(a[0]), "+v"(a[1]), "+v"(a[2]), "+v"(a[3]),
          "+v"(b[0]), "+v"(b[1]), "+v"(b[2]), "+v"(b[3]) :: "memory");
}
__device__ __forceinline__ void store_dw_mall(unsigned* p, unsigned v) {
    asm volatile("global_store_dword %0, %1, off sc0 sc1" :: "v"(p), "v"(v) : "memory");
}

__device__ __forceinline__ int tags_ok(const i32x4* r, unsigned tag) {
    unsigned m = 0;
#pragma unroll
    for (int i = 0; i < 4; ++i) {
        m |= ((unsigned)r[i][0] ^ tag); m |= ((unsigned)r[i][1] ^ tag);
        m |= ((unsigned)r[i][2] ^ tag); m |= ((unsigned)r[i][3] ^ tag);
    }
    return __all((m & 0xFFFF0000u) == 0);
}
__device__ __forceinline__ void unpack_to_lds(const i32x4* r, _Float16* base) {
#pragma unroll
    for (int t = 0; t < 2; ++t) {
        i32x4 pk;
        pk[0] = (r[2 * t][0] & 0xFFFF) | (r[2 * t][1] << 16);
        pk[1] = (r[2 * t][2] & 0xFFFF) | (r[2 * t][3] << 16);
        pk[2] = (r[2 * t + 1][0] & 0xFFFF) | (r[2 * t + 1][1] << 16);
        pk[3] = (r[2 * t + 1][2] & 0xFFFF) | (r[2 * t + 1][3] << 16);
        *(i32x4*)(base + t * 32) = pk;
    }
}

// grid 256 wgs x 256 thr. wg = (batch group g = blk&15) x (hidden slice sl = blk>>4)
// wave w = gate (i,f,g,o); weights pinned in regs as f16 MFMA B-frags.
// Layer-pipelined: iter u does layer0 step u (u<T) and layer1 step u-1 (u>=1).
// Epoch-tagged h at MALL; software-pipelined polls.
// h0: double buffer (overwrite transitively gated through entry polls).
// h1: TRIPLE buffer — closes the WAR/overwrite-deadlock race (writer of
// h1[u+2] at iter u+3 is gated via the h0 epoch chain behind every peer's
// layer-1 of iter u+1, which consumed h1[u-1]).
__global__ __launch_bounds__(256, 1) void lstm_main(
    const float* __restrict__ x, const int* __restrict__ mask,
    const float* __restrict__ Wih0, const float* __restrict__ Whh0,
    const float* __restrict__ bih0, const float* __restrict__ bhh0,
    const float* __restrict__ Wih1, const float* __restrict__ Whh1,
    const float* __restrict__ bih1, const float* __restrict__ bhh1,
    const float* __restrict__ fcw, char* __restrict__ ws)
{
    const int tid  = threadIdx.x;
    const int blk  = blockIdx.x;
    const int g    = blk & 15;    // batch group
    const int sl   = blk >> 4;    // hidden slice
    const int b0   = g * 16;
    const int j0   = sl * 16;
    const int w    = tid >> 6;
    const int lane = tid & 63;
    const int row  = lane & 15;
    const int quad = lane >> 4;
    const int kb   = quad * 8;

    float*    partials = (float*)(ws + WS_PART);
    unsigned* h0u      = (unsigned*)(ws + WS_H0);
    unsigned* h1u      = (unsigned*)(ws + WS_H1);

    __shared__ float gbuf[2048];
    __shared__ __align__(16) _Float16 hsh0[16 * 264];
    __shared__ __align__(16) _Float16 hsh1[16 * 264];

    // ---- pin weights in registers (f16 B-frags), n = gate row ----
    const int n = w * H_ + j0 + row;
    half8 wA[12], wB[16];
#pragma unroll
    for (int kt = 0; kt < 4; ++kt) wA[kt]     = cvt8(&Wih0[(size_t)n * D_ + kt * 32 + kb]);
#pragma unroll
    for (int kt = 0; kt < 8; ++kt) wA[4 + kt] = cvt8(&Whh0[(size_t)n * H_ + kt * 32 + kb]);
#pragma unroll
    for (int kt = 0; kt < 8; ++kt) wB[kt]     = cvt8(&Wih1[(size_t)n * H_ + kt * 32 + kb]);
#pragma unroll
    for (int kt = 0; kt < 8; ++kt) wB[8 + kt] = cvt8(&Whh1[(size_t)n * H_ + kt * 32 + kb]);
    const float biasA = bih0[n] + bhh0[n];
    const float biasB = bih1[n] + bhh1[n];

    const int bb    = tid >> 4;
    const int jj    = tid & 15;
    const int bglob = b0 + bb;

    int len = 0;
    {
        const int* mrow = mask + (size_t)bglob * T_ + jj * 32;
#pragma unroll
        for (int q = 0; q < 32; ++q) len += mrow[q];
#pragma unroll
        for (int o = 1; o < 16; o <<= 1) len += __shfl_xor(len, o, 16);
    }

    float c0 = 0.f, c1 = 0.f, hsave = 0.f;

    const float* xrow = x + (size_t)(b0 + row) * T_ * D_ + kb;
    // xacc for step 0
    f32x4 xacc = {0.f, 0.f, 0.f, 0.f};
#pragma unroll
    for (int kt = 0; kt < 4; ++kt)
        xacc = __builtin_amdgcn_mfma_f32_16x16x32_f16(cvt8(xrow + kt * 32), wA[kt], xacc, 0, 0, 0);

    i32x4 r0[4], r1[4];   // pre-issued h0 / h1 snapshots
    const int koff = w * 64 + quad * 8;  // this wave's k-quarter (u32 units)

    for (int u = 0; u <= T_; ++u) {
        half8 a0[8], a1[8];
        f32x4 xr[8];
        int h1ok = 1;
        const unsigned tag1 = (unsigned)(u - 1) << 16;
        // h1 triple-buffer slots (uniform scalar math, negligible)
        const int st3 = (u >= 1) ? (u - 1) % 3 : 0;  // store h1[u-1] / pre-issue h1[u-1]
        const int rd3 = (u >= 2) ? (u - 2) % 3 : 0;  // re-poll h1[u-2]

        if (u >= 1) {
            // ---- step entry: ONE wait covering store-acks + both snapshots ----
            wait_tie8(r0, r1);
            const unsigned tag0 = (unsigned)u << 16;
            const unsigned* p0 = h0u + ((size_t)((u - 1) & 1) * B_ + (b0 + row)) * H_ + koff;
            int guard = 0;
            while (!tags_ok(r0, tag0)) {
                poll4_wait(p0, r0);
                if (++guard > (1 << 15)) break;  // bounded: fail loud, never hang
            }
            h1ok = (u >= 2) ? tags_ok(r1, tag1) : 1;
            // x prefetch for u+1 (plain cached loads; latency hidden in slack)
            {
                const int tn = (u + 1 < T_) ? (u + 1) : (T_ - 1);
                const f32x4* q = (const f32x4*)(xrow + (size_t)tn * D_);
#pragma unroll
                for (int kt = 0; kt < 4; ++kt) { xr[2 * kt] = q[kt * 8]; xr[2 * kt + 1] = q[kt * 8 + 1]; }
            }
            // unpack h0 -> LDS, share across waves, read A-frags
            unpack_to_lds(r0, hsh0 + row * 264 + koff);
            __syncthreads();  // sync A
#pragma unroll
            for (int kt = 0; kt < 8; ++kt)
                a0[kt] = *(const half8*)(hsh0 + row * 264 + kt * 32 + quad * 8);
        } else {
            const f32x4* q = (const f32x4*)(xrow + (size_t)1 * D_);
#pragma unroll
            for (int kt = 0; kt < 4; ++kt) { xr[2 * kt] = q[kt * 8]; xr[2 * kt + 1] = q[kt * 8 + 1]; }
        }

        // ================= layer 0 (critical recurrence) =================
        if (u < T_) {
            f32x4 acc0 = xacc;
            if (u >= 1) {
#pragma unroll
                for (int kt = 0; kt < 8; ++kt)
                    acc0 = __builtin_amdgcn_mfma_f32_16x16x32_f16(a0[kt], wA[4 + kt], acc0, 0, 0, 0);
            }
#pragma unroll
            for (int r = 0; r < 4; ++r)
                gbuf[w * 256 + (quad * 4 + r) * 16 + row] = acc0[r] + biasA;
            __syncthreads();  // sync B
            const int idx = bb * 16 + jj;
            float gi = fast_sig(gbuf[idx]);
            float gf = fast_sig(gbuf[256 + idx]);
            float gg = fast_tanh(gbuf[512 + idx]);
            float go = fast_sig(gbuf[768 + idx]);
            c0 = gf * c0 + gi * gg;
            float h0v = go * fast_tanh(c0);
            union { _Float16 h; unsigned short s; } cv; cv.h = (_Float16)h0v;
            store_dw_mall(h0u + ((size_t)(u & 1) * B_ + bglob) * H_ + j0 + jj,
                          ((unsigned)(u + 1) << 16) | cv.s);  // h0[u] fires EARLY
        }
        __builtin_amdgcn_sched_barrier(0);  // keep layer1 below the h0 store

        // ================= layer 1 (one step of slack) =================
        if (u >= 1) {
            f32x4 acc1 = {0.f, 0.f, 0.f, 0.f};
#pragma unroll
            for (int kt = 0; kt < 8; ++kt)
                acc1 = __builtin_amdgcn_mfma_f32_16x16x32_f16(a0[kt], wB[kt], acc1, 0, 0, 0);
            if (u >= 2) {
                const unsigned* p1 = h1u + ((size_t)rd3 * B_ + (b0 + row)) * H_ + koff;
                int guard = 0;
                while (!h1ok) {        // rare: slack absorbs the re-poll
                    poll4_wait(p1, r1);
                    h1ok = tags_ok(r1, tag1);
                    if (++guard > (1 << 15)) break;
                }
                unpack_to_lds(r1, hsh1 + row * 264 + koff);
                __syncthreads();  // sync C
#pragma unroll
                for (int kt = 0; kt < 8; ++kt)
                    a1[kt] = *(const half8*)(hsh1 + row * 264 + kt * 32 + quad * 8);
#pragma unroll
                for (int kt = 0; kt < 8; ++kt)
                    acc1 = __builtin_amdgcn_mfma_f32_16x16x32_f16(a1[kt], wB[8 + kt], acc1, 0, 0, 0);
            }
#pragma unroll
            for (int r = 0; r < 4; ++r)
                gbuf[1024 + w * 256 + (quad * 4 + r) * 16 + row] = acc1[r] + biasB;
            __syncthreads();  // sync D
            const int idx = bb * 16 + jj;
            float gi = fast_sig(gbuf[1024 + idx]);
            float gf = fast_sig(gbuf[1024 + 256 + idx]);
            float gg = fast_tanh(gbuf[1024 + 512 + idx]);
            float go = fast_sig(gbuf[1024 + 768 + idx]);
            c1 = gf * c1 + gi * gg;
            float h1v = go * fast_tanh(c1);
            union { _Float16 h; unsigned short s; } cv; cv.h = (_Float16)h1v;
            store_dw_mall(h1u + ((size_t)st3 * B_ + bglob) * H_ + j0 + jj,
                          ((unsigned)u << 16) | cv.s);
            if (u == len) hsave = h1v;
        }

        // xacc for step u+1 FIRST (delays pre-issue -> higher snapshot hit rate)
        if (u < T_ - 1) {
            f32x4 t = {0.f, 0.f, 0.f, 0.f};
#pragma unroll
            for (int kt = 0; kt < 4; ++kt)
                t = __builtin_amdgcn_mfma_f32_16x16x32_f16(cvt8v(xr[2 * kt], xr[2 * kt + 1]), wA[kt], t, 0, 0, 0);
            xacc = t;
        }

        // ---- pre-issue next step's snapshots (fire-and-forget, as late as possible) ----
        if (u < T_) {
            const int v = u + 1;
            const unsigned* q0 = h0u + ((size_t)((v - 1) & 1) * B_ + (b0 + row)) * H_ + koff;
            const unsigned* q1 = (v >= 2)
                ? h1u + ((size_t)st3 * B_ + (b0 + row)) * H_ + koff   // slot of h1[v-2]=h1[u-1]
                : q0;
            poll4_issue(q0, r0);
            poll4_issue(q1, r1);
        }
    }

    float part = hsave * fcw[j0 + jj];
#pragma unroll
    for (int o = 1; o < 16; o <<= 1) part += __shfl_xor(part, o, 16);
    if (jj == 0) partials[sl * B_ + bglob] = part;
}

__global__ void lstm_fc(const float* __restrict__ fcb, const char* __restrict__ ws,
                        float* __restrict__ out) {
    const int b = threadIdx.x;
    const float* partials = (const float*)(ws + WS_PART);
    float s = fcb[0];
#pragma unroll
    for (int sl = 0; sl < 16; ++sl) s += partials[sl * B_ + b];
    out[b] = s;
}

extern "C" void kernel_launch(void* const* d_in, const int* in_sizes, int n_in,
                              void* d_out, int out_size, void* d_ws, size_t ws_size,
                              hipStream_t stream) {
    const float* xx    = (const float*)d_in[0];
    const int*   mask  = (const int*)d_in[1];
    const float* Wih0  = (const float*)d_in[2];
    const float* Whh0  = (const float*)d_in[3];
    const float* bih0  = (const float*)d_in[4];
    const float* bhh0  = (const float*)d_in[5];
    const float* Wih1  = (const float*)d_in[6];
    const float* Whh1  = (const float*)d_in[7];
    const float* bih1  = (const float*)d_in[8];
    const float* bhh1  = (const float*)d_in[9];
    const float* fcw   = (const float*)d_in[10];
    const float* fcb   = (const float*)d_in[11];

    lstm_main<<<dim3(256), dim3(256), 0, stream>>>(
        xx, mask, Wih0, Whh0, bih0, bhh0, Wih1, Whh1, bih1, bhh1, fcw, (char*)d_ws);
    lstm_fc<<<dim3(1), dim3(256), 0, stream>>>(fcb, (const char*)d_ws, (float*)d_out);
}